// Round 3
// 469.439 us; speedup vs baseline: 1.1318x; 1.1318x over previous
//
#include <hip/hip_runtime.h>
#include <stdint.h>

#define MM 8192
#define NN 4096
#define KK 4096
#define BM 256
#define BN 256
#define BK 64
#define NT (KK / BK)   // 64 K-tiles

typedef __attribute__((ext_vector_type(8))) short short8;
typedef __attribute__((ext_vector_type(4))) float floatx4;
typedef int int4a __attribute__((ext_vector_type(4), aligned(4)));  // 4B-aligned 16B load

// fp32 -> bf16 round-to-nearest-even
__device__ inline unsigned short f2bf(float f) {
    unsigned int u = __float_as_uint(f);
    u += 0x7FFFu + ((u >> 16) & 1u);
    return (unsigned short)(u >> 16);
}

// Convert x [8192,4096] fp32 -> bf16, 8 elems/thread, coalesced.
__global__ void prep_x_kernel(const float* __restrict__ x, unsigned short* __restrict__ xb) {
    size_t i = (size_t)blockIdx.x * 256 + threadIdx.x;
    const float4* x4 = (const float4*)x;
    float4 v0 = x4[i * 2];
    float4 v1 = x4[i * 2 + 1];
    ushort4 o0, o1;
    o0.x = f2bf(v0.x); o0.y = f2bf(v0.y); o0.z = f2bf(v0.z); o0.w = f2bf(v0.w);
    o1.x = f2bf(v1.x); o1.y = f2bf(v1.y); o1.z = f2bf(v1.z); o1.w = f2bf(v1.w);
    *(ushort4*)(xb + i * 8)     = o0;
    *(ushort4*)(xb + i * 8 + 4) = o1;
}

// vals (8191 fp32) -> two bf16 copies: vlo[i]=vals[i], vhi[i]=vals[i+1].
__global__ void prep_vals_kernel(const float* __restrict__ vals,
                                 unsigned short* __restrict__ vlo,
                                 unsigned short* __restrict__ vhi) {
    int i = blockIdx.x * 256 + threadIdx.x;
    if (i < KK + NN - 1) {
        unsigned short s = f2bf(vals[i]);
        vlo[i] = s;
        if (i > 0) vhi[i - 1] = s;
    }
}

#define GLOAD_LDS16(g, l)                                              \
    __builtin_amdgcn_global_load_lds(                                  \
        (__attribute__((address_space(1))) void*)(g),                  \
        (__attribute__((address_space(3))) void*)(l), 16, 0, 0)

// 256x256 tile, 8 waves (2Mx4N), 4-phase/K-tile counted-vmcnt schedule (T3+T4+T5).
// A-only LDS staging (4 x 32KB rotating buffers, XOR-8 swizzle, depth-2 prefetch);
// B (Toeplitz) comes from L1-resident vals copies, prefetched 1 tile ahead into
// ping-pong register sets. Raw s_barrier everywhere; vmcnt(12) once per K-tile
// guarantees the NEXT tile's 4 global_load_lds landed while keeping the 8 b-loads
// + 4 GLLs issued after them in flight (never drain to 0 in the main loop).
__global__ __launch_bounds__(512, 2) void gemm_kernel(
        const unsigned short* __restrict__ A,
        const unsigned short* __restrict__ vlo,
        const unsigned short* __restrict__ vhi,
        float* __restrict__ C) {
    __shared__ unsigned short ldsA[4][BM * BK];   // 4 x 32 KB = 128 KB

    const int tid  = threadIdx.x;
    const int lane = tid & 63;
    const int w    = tid >> 6;            // 0..7
    const int n0 = blockIdx.x * BN;
    const int m0 = blockIdx.y * BM;

    const int quad = lane >> 4;           // 0..3 (MFMA k-group)
    const int l16  = lane & 15;
    const int wm   = (w >> 2) * 128;      // wave row: 2 waves in M
    const int wn   = (w & 3) * 64;        // wave col: 4 waves in N

    // ---- A staging: wave w stages rows [w*32, w*32+32), 4 GLL of 8 rows each.
    // Lane l -> row (l>>3), slot (l&7); slot s of row r holds global chunk s^(r&7).
    const int lr8 = lane >> 3;
    const int cg  = (lane & 7) ^ (lr8 & 7);
    const unsigned short* aSrc = A + (size_t)(m0 + w * 32 + lr8) * KK + cg * 8;
    const int sBase = (w * 32) * BK;

    // ---- B pointers: idx = 4095 - (n0+wn+l16+j*16) + quad*8 (+k). Dual copy
    // (vlo/vhi) makes every even element offset 4B-aligned for dwordx4 loads.
    const unsigned short* bptr[4];
#pragma unroll
    for (int j = 0; j < 4; ++j) {
        int idx0 = (NN - 1) - (n0 + wn + l16) - j * 16 + quad * 8;
        bptr[j] = (idx0 & 1) ? (vhi + (idx0 - 1)) : (vlo + idx0);
    }

    floatx4 acc[8][4] = {};
    short8 b0r[8], b1r[8];                // ping-pong B fragment sets (tile parity)

#define STAGE1(BI, T, G)                                               \
    GLOAD_LDS16(aSrc + (size_t)(G) * 8 * KK + (size_t)(T) * BK,        \
                &ldsA[BI][sBase + (G) * 8 * BK])

#define LOADB(DST, T)                                                  \
    do {                                                               \
        _Pragma("unroll")                                              \
        for (int j = 0; j < 4; ++j) {                                  \
            _Pragma("unroll")                                          \
            for (int kh = 0; kh < 2; ++kh) {                           \
                int4a t_ = *(const int4a*)(bptr[j] + (size_t)(T) * BK + kh * 32); \
                __builtin_memcpy(&(DST)[j * 2 + kh], &t_, 16);         \
            }                                                          \
        }                                                              \
    } while (0)

#define AFRAG(AF, BI, P)                                               \
    do {                                                               \
        _Pragma("unroll")                                              \
        for (int ii = 0; ii < 2; ++ii) {                               \
            _Pragma("unroll")                                          \
            for (int kh = 0; kh < 2; ++kh)                             \
                (AF)[ii * 2 + kh] = *(const short8*)&ldsA[BI][         \
                    (wm + (2 * (P) + ii) * 16 + l16) * BK +            \
                    (((kh * 4 + quad) ^ (l16 & 7)) * 8)];              \
        }                                                              \
    } while (0)

#define MFMA16(AF, BS, P)                                              \
    do {                                                               \
        _Pragma("unroll")                                              \
        for (int ii = 0; ii < 2; ++ii) {                               \
            _Pragma("unroll")                                          \
            for (int j = 0; j < 4; ++j) {                              \
                _Pragma("unroll")                                      \
                for (int kh = 0; kh < 2; ++kh)                         \
                    acc[2 * (P) + ii][j] =                             \
                        __builtin_amdgcn_mfma_f32_16x16x32_bf16(       \
                            (AF)[ii * 2 + kh], (BS)[j * 2 + kh],       \
                            acc[2 * (P) + ii][j], 0, 0, 0);            \
            }                                                          \
        }                                                              \
    } while (0)

#define SB()    __builtin_amdgcn_s_barrier()
#define PRIO(x) __builtin_amdgcn_s_setprio(x)
#define WAITV(N) asm volatile("s_waitcnt vmcnt(" #N ")" ::: "memory")

    // ---- prologue: GLL(0), b(0), GLL(1); wait tile0 landed (12 newer in flight)
#pragma unroll
    for (int g = 0; g < 4; ++g) STAGE1(0, 0, g);
    LOADB(b0r, 0);
#pragma unroll
    for (int g = 0; g < 4; ++g) STAGE1(1, 1, g);
    WAITV(12);
    SB();

    // Tile t reads buf[t&3]; stages tile t+2 into buf[(t+2)&3] (freed at t-2's
    // end); loads b(t+1) in phase 0. End-of-tile WAITV(12) = all GLL(t+1) done
    // (newer: 8 b(t+1) + 4 GLL(t+2) stay in flight). 2 raw barriers per phase
    // keep the 2 waves/SIMD in alternating ds_read/MFMA roles; setprio(1)
    // keeps the matrix pipe fed (T5).
#define TILE(BI, T, BCUR, BNXT, DOB, DOST, LW)                         \
    do {                                                               \
        short8 af_[4];                                                 \
        AFRAG(af_, BI, 0);                                             \
        if (DOB) LOADB(BNXT, (T) + 1);                                 \
        if (DOST) STAGE1(((BI) + 2) & 3, (T) + 2, 0);                  \
        SB(); PRIO(1); MFMA16(af_, BCUR, 0); PRIO(0); SB();            \
        AFRAG(af_, BI, 1);                                             \
        if (DOST) STAGE1(((BI) + 2) & 3, (T) + 2, 1);                  \
        SB(); PRIO(1); MFMA16(af_, BCUR, 1); PRIO(0); SB();            \
        AFRAG(af_, BI, 2);                                             \
        if (DOST) STAGE1(((BI) + 2) & 3, (T) + 2, 2);                  \
        SB(); PRIO(1); MFMA16(af_, BCUR, 2); PRIO(0); SB();            \
        AFRAG(af_, BI, 3);                                             \
        if (DOST) STAGE1(((BI) + 2) & 3, (T) + 2, 3);                  \
        SB(); PRIO(1); MFMA16(af_, BCUR, 3); PRIO(0);                  \
        LW; SB();                                                      \
    } while (0)

    for (int u = 0; u < 15; ++u) {
        const int t = u * 4;
        TILE(0, t + 0, b0r, b1r, 1, 1, WAITV(12));
        TILE(1, t + 1, b1r, b0r, 1, 1, WAITV(12));
        TILE(2, t + 2, b0r, b1r, 1, 1, WAITV(12));
        TILE(3, t + 3, b1r, b0r, 1, 1, WAITV(12));
    }
    // Peeled drain: tiles 60..63 (stages 62,63 still issued; then taper waits)
    TILE(0, 60, b0r, b1r, 1, 1, WAITV(12));
    TILE(1, 61, b1r, b0r, 1, 1, WAITV(12));
    TILE(2, 62, b0r, b1r, 1, 0, WAITV(8));
    TILE(3, 63, b1r, b0r, 0, 0, (void)0);

    // Epilogue: C/D layout col = lane&15, row = quad*4 + reg (m89-verified)
    float* cW = C + (size_t)(m0 + wm) * NN + (n0 + wn);
#pragma unroll
    for (int i = 0; i < 8; ++i) {
#pragma unroll
        for (int j = 0; j < 4; ++j) {
            float* cp = cW + (size_t)(i * 16 + quad * 4) * NN + j * 16 + l16;
#pragma unroll
            for (int r = 0; r < 4; ++r)
                cp[(size_t)r * NN] = acc[i][j][r];
        }
    }
#undef TILE
#undef STAGE1
#undef LOADB
#undef AFRAG
#undef MFMA16
}

extern "C" void kernel_launch(void* const* d_in, const int* in_sizes, int n_in,
                              void* d_out, int out_size, void* d_ws, size_t ws_size,
                              hipStream_t stream) {
    const float* x    = (const float*)d_in[0];
    const float* vals = (const float*)d_in[1];
    float* out = (float*)d_out;

    unsigned short* xb  = (unsigned short*)d_ws;          // 67.1 MB
    unsigned short* vlo = xb + (size_t)MM * KK;
    unsigned short* vhi = vlo + 16384;

    prep_x_kernel<<<MM * KK / 8 / 256, 256, 0, stream>>>(x, xb);
    prep_vals_kernel<<<(KK + NN - 1 + 255) / 256, 256, 0, stream>>>(vals, vlo, vhi);

    dim3 grid(NN / BN, MM / BM);
    gemm_kernel<<<grid, 512, 0, stream>>>(xb, vlo, vhi, out);
}